// Round 1
// baseline (1919.048 us; speedup 1.0000x reference)
//
#include <hip/hip_runtime.h>
#include <math.h>

#define HDIM 256
#define NCLS 9

// Persistent fp32 RNN layer: each block owns ROWS batch rows, runs all T steps.
// 512 threads: j = tid&255 (output column), half = tid>>8 (which half of the
// i-summation). Each thread holds U[half*128 .. half*128+128)[j] in registers.
template<int ROWS>
__global__ __launch_bounds__(512, 2) void rnn_kernel(
    const float* __restrict__ seq,   // [B, T] (layer1: x[b,t,0]; layer2: h1[b,t])
    int T,
    const float* __restrict__ W,     // [256]  (W[0,:])
    const float* __restrict__ U,     // [256,256] row-major U[i*256+j]
    const float* __restrict__ bias,  // [256]
    float* __restrict__ out)         // [B, 256]
{
    const int tid  = threadIdx.x;
    const int j    = tid & 255;
    const int half = tid >> 8;   // 0 or 1
    const int b0   = blockIdx.x * ROWS;

    __shared__ float h_bc[ROWS][HDIM];     // broadcast hidden state
    __shared__ float part[ROWS][HDIM];     // cross-half partial sums
    __shared__ float s_chunk[ROWS][256];   // prefetched sequence values

    // Load U half-column into registers (coalesced: lanes vary in j).
    float u[128];
    const float* Up = U + (half * 128) * HDIM + j;
#pragma unroll
    for (int k = 0; k < 128; ++k) u[k] = Up[k * HDIM];

    const float wj = W[j];
    const float bj = bias[j];

    if (tid < HDIM) {
#pragma unroll
        for (int r = 0; r < ROWS; ++r) h_bc[r][tid] = 0.0f;
    }
    __syncthreads();

    const int base = half * 128;

    for (int t = 0; t < T; ++t) {
        if ((t & 255) == 0) {
            // prefetch next 256 sequence values per row
            if (tid < 256) {
                const int tt = t + tid;
#pragma unroll
                for (int r = 0; r < ROWS; ++r)
                    s_chunk[r][tid] = (tt < T) ? seq[(b0 + r) * T + tt] : 0.0f;
            }
            __syncthreads();
        }

        float acc[ROWS];
#pragma unroll
        for (int r = 0; r < ROWS; ++r) acc[r] = 0.0f;

        // acc[r] = sum_{i in half} h[r][i] * U[i][j]; h reads are wave-uniform
        // (broadcast, conflict-free), U is in registers.
#pragma unroll
        for (int k = 0; k < 128; k += 4) {
#pragma unroll
            for (int r = 0; r < ROWS; ++r) {
                const float4 h4 = *reinterpret_cast<const float4*>(&h_bc[r][base + k]);
                acc[r] += u[k + 0] * h4.x;
                acc[r] += u[k + 1] * h4.y;
                acc[r] += u[k + 2] * h4.z;
                acc[r] += u[k + 3] * h4.w;
            }
        }

        if (half == 1) {
#pragma unroll
            for (int r = 0; r < ROWS; ++r) part[r][j] = acc[r];
        }
        __syncthreads();
        if (half == 0) {
#pragma unroll
            for (int r = 0; r < ROWS; ++r) {
                const float v = acc[r] + part[r][j]
                              + s_chunk[r][t & 255] * wj + bj;
                h_bc[r][j] = tanhf(v);
            }
        }
        __syncthreads();
    }

    if (tid < HDIM) {
#pragma unroll
        for (int r = 0; r < ROWS; ++r) out[(b0 + r) * HDIM + tid] = h_bc[r][tid];
    }
}

// Tiny MLP head: one block per batch row, 128 threads.
__global__ __launch_bounds__(128) void mlp_kernel(
    const float* __restrict__ h2,    // [B,256]
    const float* __restrict__ Wd1, const float* __restrict__ bd1,  // [256,128],[128]
    const float* __restrict__ Wd2, const float* __restrict__ bd2,  // [128,64],[64]
    const float* __restrict__ Wd3, const float* __restrict__ bd3,  // [64,32],[32]
    const float* __restrict__ Wd4, const float* __restrict__ bd4,  // [32,9],[9]
    float* __restrict__ out)         // [B,9]
{
    const int b   = blockIdx.x;
    const int tid = threadIdx.x;

    __shared__ float hin[256];
    __shared__ float z1[128];
    __shared__ float z2[64];
    __shared__ float z3[32];

    hin[tid]       = h2[b * 256 + tid];
    hin[tid + 128] = h2[b * 256 + tid + 128];
    __syncthreads();

    {
        float a = bd1[tid];
#pragma unroll 8
        for (int i = 0; i < 256; ++i) a += hin[i] * Wd1[i * 128 + tid];
        z1[tid] = fmaxf(a, 0.0f);
    }
    __syncthreads();
    if (tid < 64) {
        float a = bd2[tid];
#pragma unroll 8
        for (int i = 0; i < 128; ++i) a += z1[i] * Wd2[i * 64 + tid];
        z2[tid] = fmaxf(a, 0.0f);
    }
    __syncthreads();
    if (tid < 32) {
        float a = bd3[tid];
#pragma unroll 8
        for (int i = 0; i < 64; ++i) a += z2[i] * Wd3[i * 32 + tid];
        z3[tid] = fmaxf(a, 0.0f);
    }
    __syncthreads();
    if (tid < NCLS) {
        float a = bd4[tid];
#pragma unroll
        for (int i = 0; i < 32; ++i) a += z3[i] * Wd4[i * NCLS + tid];
        out[b * NCLS + tid] = a;
    }
}

extern "C" void kernel_launch(void* const* d_in, const int* in_sizes, int n_in,
                              void* d_out, int out_size, void* d_ws, size_t ws_size,
                              hipStream_t stream) {
    const float* x   = (const float*)d_in[0];   // [512,1024,1]
    const float* W1  = (const float*)d_in[1];   // [1,256]
    const float* U1  = (const float*)d_in[2];   // [256,256]
    const float* b1  = (const float*)d_in[3];   // [256]
    const float* W2  = (const float*)d_in[4];   // [1,256]
    const float* U2  = (const float*)d_in[5];   // [256,256]
    const float* b2  = (const float*)d_in[6];   // [256]
    const float* Wd1 = (const float*)d_in[7];   // [256,128]
    const float* bd1 = (const float*)d_in[8];
    const float* Wd2 = (const float*)d_in[9];   // [128,64]
    const float* bd2 = (const float*)d_in[10];
    const float* Wd3 = (const float*)d_in[11];  // [64,32]
    const float* bd3 = (const float*)d_in[12];
    const float* Wd4 = (const float*)d_in[13];  // [32,9]
    const float* bd4 = (const float*)d_in[14];

    float* out = (float*)d_out;                 // [512,9]
    float* ws  = (float*)d_ws;
    float* h1  = ws;                            // 512*256 floats
    float* h2  = ws + 512 * 256;                // 512*256 floats

    const int B = 512;
    const int ROWS = 2;

    rnn_kernel<ROWS><<<B / ROWS, 512, 0, stream>>>(x, 1024, W1, U1, b1, h1);
    rnn_kernel<ROWS><<<B / ROWS, 512, 0, stream>>>(h1, 256, W2, U2, b2, h2);
    mlp_kernel<<<B, 128, 0, stream>>>(h2, Wd1, bd1, Wd2, bd2, Wd3, bd3, Wd4, bd4, out);
}

// Round 2
// 923.144 us; speedup vs baseline: 2.0788x; 2.0788x over previous
//
#include <hip/hip_runtime.h>
#include <math.h>

#define NCLS 9

typedef __attribute__((ext_vector_type(8))) short short8;
typedef __attribute__((ext_vector_type(4))) float f32x4;

__device__ __forceinline__ unsigned short f2bf(float f) {
    unsigned int u = __float_as_uint(f);
    return (unsigned short)((u + 0x7fffu + ((u >> 16) & 1u)) >> 16);  // RNE
}

__device__ __forceinline__ short8 as_s8(uint4 v) {
    union { uint4 u; short8 s; } x; x.u = v; return x.s;
}

__device__ __forceinline__ float fast_tanh(float x) {
    // tanh(x) = 1 - 2/(e^{2x}+1); exp->inf / ->0 saturate correctly to +/-1
    float e = __expf(2.0f * x);
    return 1.0f - 2.0f * __builtin_amdgcn_rcpf(e + 1.0f);
}

// Persistent MFMA RNN: 32 blocks x 16 batch rows, 512 threads (8 waves).
// U held in registers as MFMA B-fragments (pinned). h double-buffered in LDS
// as bf16 with XOR swizzle ((row&7)<<4) to kill the stride-512B bank conflict.
__global__ __launch_bounds__(512, 2) void rnn_mfma_kernel(
    const float* __restrict__ seq,   // [B, T]
    int T,
    const float* __restrict__ W,     // [256]
    const float* __restrict__ U,     // [256,256] row-major
    const float* __restrict__ bias,  // [256]
    float* __restrict__ out)         // [B, 256] fp32
{
    const int tid  = threadIdx.x;
    const int wave = tid >> 6;
    const int lane = tid & 63;
    const int g    = lane >> 4;   // 16-lane group 0..3
    const int l16  = lane & 15;
    const int b0   = blockIdx.x << 4;

    __shared__ unsigned char h_lds[2][8192];   // [16 rows][256 k] bf16, swizzled
    __shared__ float s_chunk[128][16];         // seq prefetch [t][row]

    // ---- one-time: load U columns as B-fragments, bf16, into registers ----
    // B-frag layout (16x16x32): lane l -> col = l&15, k = kk*32 + (l>>4)*8 + i.
    // Any bijective k-map within a tile is fine as long as A uses the same one.
    uint4 bfrag0[8], bfrag1[8];
    {
        const int col0 = wave * 32 + l16;
        #pragma unroll
        for (int kk = 0; kk < 8; ++kk) {
            unsigned int t0[4], t1[4];
            #pragma unroll
            for (int w2 = 0; w2 < 4; ++w2) {
                const int k0 = kk * 32 + g * 8 + 2 * w2;
                t0[w2] = (unsigned)f2bf(U[k0 * 256 + col0])
                       | ((unsigned)f2bf(U[(k0 + 1) * 256 + col0]) << 16);
                t1[w2] = (unsigned)f2bf(U[k0 * 256 + col0 + 16])
                       | ((unsigned)f2bf(U[(k0 + 1) * 256 + col0 + 16]) << 16);
            }
            bfrag0[kk] = make_uint4(t0[0], t0[1], t0[2], t0[3]);
            bfrag1[kk] = make_uint4(t1[0], t1[1], t1[2], t1[3]);
        }
    }
    // Pin fragments: opaque asm output cannot be rematerialized inside the loop
    // (round-1 failure mode: compiler sank loop-invariant loads, VGPR=84).
    #pragma unroll
    for (int kk = 0; kk < 8; ++kk) {
        asm volatile("" : "+v"(bfrag0[kk].x), "+v"(bfrag0[kk].y),
                          "+v"(bfrag0[kk].z), "+v"(bfrag0[kk].w));
        asm volatile("" : "+v"(bfrag1[kk].x), "+v"(bfrag1[kk].y),
                          "+v"(bfrag1[kk].z), "+v"(bfrag1[kk].w));
    }

    const float wv0 = W[wave * 32 + l16];
    const float wv1 = W[wave * 32 + 16 + l16];
    const float bv0 = bias[wave * 32 + l16];
    const float bv1 = bias[wave * 32 + 16 + l16];

    // zero h buffer 0 (h_0 = 0)
    for (int idx = tid; idx < 2048; idx += 512)
        ((unsigned int*)h_lds[0])[idx] = 0u;

    const unsigned swzA   = (unsigned)((l16 & 7) << 4);
    const int arow_off    = l16 * 512 + g * 16;  // A row = l&15, k-group offset
    const int crow        = g * 4;               // C rows = (l>>4)*4 + r

    for (int t = 0; t < T; ++t) {
        if ((t & 127) == 0) {
            // prefetch 128 steps x 16 rows of seq (also covers h-zero barrier at t=0)
            for (int idx = tid; idx < 2048; idx += 512) {
                const int dt = idx >> 4, row = idx & 15;
                s_chunk[dt][row] = seq[(b0 + row) * T + (t + dt)];
            }
            __syncthreads();
        }
        const int cur = t & 1;
        const int nxt = cur ^ 1;

        const float4 sv = *(const float4*)&s_chunk[t & 127][crow];

        // A-fragments: full h (16x256) per wave, 8 x ds_read_b128, swizzled
        uint4 a[8];
        #pragma unroll
        for (int kk = 0; kk < 8; ++kk)
            a[kk] = *(const uint4*)&h_lds[cur][(unsigned)(arow_off + kk * 64) ^ swzA];

        f32x4 acc0 = {0.f, 0.f, 0.f, 0.f};
        f32x4 acc1 = {0.f, 0.f, 0.f, 0.f};
        #pragma unroll
        for (int kk = 0; kk < 8; ++kk) {
            acc0 = __builtin_amdgcn_mfma_f32_16x16x32_bf16(as_s8(a[kk]), as_s8(bfrag0[kk]), acc0, 0, 0, 0);
            acc1 = __builtin_amdgcn_mfma_f32_16x16x32_bf16(as_s8(a[kk]), as_s8(bfrag1[kk]), acc1, 0, 0, 0);
        }

        const float svr[4] = {sv.x, sv.y, sv.z, sv.w};
        #pragma unroll
        for (int r = 0; r < 4; ++r) {
            const int row = crow + r;
            const unsigned sw = (unsigned)((row & 7) << 4);
            const float h0 = fast_tanh(acc0[r] + svr[r] * wv0 + bv0);
            const float h1 = fast_tanh(acc1[r] + svr[r] * wv1 + bv1);
            *(unsigned short*)&h_lds[nxt][(unsigned)(row * 512 + (wave * 32 + l16) * 2) ^ sw] = f2bf(h0);
            *(unsigned short*)&h_lds[nxt][(unsigned)(row * 512 + (wave * 32 + 16 + l16) * 2) ^ sw] = f2bf(h1);
            if (t == T - 1) {
                out[(b0 + row) * 256 + wave * 32 + l16]      = h0;
                out[(b0 + row) * 256 + wave * 32 + 16 + l16] = h1;
            }
        }
        __syncthreads();
    }
}

// Tiny MLP head: one block per batch row, 128 threads.
__global__ __launch_bounds__(128) void mlp_kernel(
    const float* __restrict__ h2,
    const float* __restrict__ Wd1, const float* __restrict__ bd1,
    const float* __restrict__ Wd2, const float* __restrict__ bd2,
    const float* __restrict__ Wd3, const float* __restrict__ bd3,
    const float* __restrict__ Wd4, const float* __restrict__ bd4,
    float* __restrict__ out)
{
    const int b   = blockIdx.x;
    const int tid = threadIdx.x;

    __shared__ float hin[256];
    __shared__ float z1[128];
    __shared__ float z2[64];
    __shared__ float z3[32];

    hin[tid]       = h2[b * 256 + tid];
    hin[tid + 128] = h2[b * 256 + tid + 128];
    __syncthreads();

    {
        float a = bd1[tid];
#pragma unroll 8
        for (int i = 0; i < 256; ++i) a += hin[i] * Wd1[i * 128 + tid];
        z1[tid] = fmaxf(a, 0.0f);
    }
    __syncthreads();
    if (tid < 64) {
        float a = bd2[tid];
#pragma unroll 8
        for (int i = 0; i < 128; ++i) a += z1[i] * Wd2[i * 64 + tid];
        z2[tid] = fmaxf(a, 0.0f);
    }
    __syncthreads();
    if (tid < 32) {
        float a = bd3[tid];
#pragma unroll 8
        for (int i = 0; i < 64; ++i) a += z2[i] * Wd3[i * 32 + tid];
        z3[tid] = fmaxf(a, 0.0f);
    }
    __syncthreads();
    if (tid < NCLS) {
        float a = bd4[tid];
#pragma unroll
        for (int i = 0; i < 32; ++i) a += z3[i] * Wd4[i * NCLS + tid];
        out[b * NCLS + tid] = a;
    }
}

extern "C" void kernel_launch(void* const* d_in, const int* in_sizes, int n_in,
                              void* d_out, int out_size, void* d_ws, size_t ws_size,
                              hipStream_t stream) {
    const float* x   = (const float*)d_in[0];
    const float* W1  = (const float*)d_in[1];
    const float* U1  = (const float*)d_in[2];
    const float* b1  = (const float*)d_in[3];
    const float* W2  = (const float*)d_in[4];
    const float* U2  = (const float*)d_in[5];
    const float* b2  = (const float*)d_in[6];
    const float* Wd1 = (const float*)d_in[7];
    const float* bd1 = (const float*)d_in[8];
    const float* Wd2 = (const float*)d_in[9];
    const float* bd2 = (const float*)d_in[10];
    const float* Wd3 = (const float*)d_in[11];
    const float* bd3 = (const float*)d_in[12];
    const float* Wd4 = (const float*)d_in[13];
    const float* bd4 = (const float*)d_in[14];

    float* out = (float*)d_out;
    float* ws  = (float*)d_ws;
    float* h1  = ws;                  // 512*256 fp32
    float* h2  = ws + 512 * 256;      // 512*256 fp32

    rnn_mfma_kernel<<<32, 512, 0, stream>>>(x, 1024, W1, U1, b1, h1);
    rnn_mfma_kernel<<<32, 512, 0, stream>>>(h1, 256, W2, U2, b2, h2);
    mlp_kernel<<<512, 128, 0, stream>>>(h2, Wd1, bd1, Wd2, bd2, Wd3, bd3, Wd4, bd4, out);
}